// Round 4
// baseline (862.084 us; speedup 1.0000x reference)
//
#include <hip/hip_runtime.h>

#define N_NODES  50000
#define N_EDGES  800000
#define N_GRAPHS 128
#define FDIM     256

typedef __attribute__((ext_vector_type(8))) short short8;
typedef __attribute__((ext_vector_type(4))) float f32x4;

__device__ __forceinline__ unsigned short f2bf(float f) {
    union { float f; unsigned int u; } v; v.f = f;
    unsigned int x = v.u;
    unsigned int r = (x + 0x7FFFu + ((x >> 16) & 1u)) >> 16;
    return (unsigned short)r;
}

__device__ __forceinline__ float bf2f(unsigned short u) {
    union { unsigned int i; float f; } v;
    v.i = ((unsigned int)u) << 16;
    return v.f;
}

// ---------------- degree build ----------------

__global__ void k_zero(float* deg, int* cnt, int n) {
    int i = blockIdx.x * blockDim.x + threadIdx.x;
    if (i < n) { deg[i] = 0.0f; cnt[i] = 0; }
}

__global__ void k_deg(const int* __restrict__ dst, const float* __restrict__ ea,
                      float* deg, int* cnt, int E) {
    int e = blockIdx.x * blockDim.x + threadIdx.x;
    if (e < E) {
        int d = dst[e];
        atomicAdd(&deg[d], ea[e]);
        atomicAdd(&cnt[d], 1);
    }
}

// ---------------- 3-phase exclusive scan (dinv folded into phase 1) ----------------

__global__ __launch_bounds__(1024) void k_scan1(const int* __restrict__ cnt,
                                                const float* __restrict__ deg,
                                                float* __restrict__ dinv,
                                                int* row_ptr, int* partial, int n) {
    __shared__ int buf[2][1024];
    int tid = threadIdx.x;
    int i = blockIdx.x * 1024 + tid;
    if (i < n) dinv[i] = rsqrtf(deg[i] + 1.0f);
    int v = (i < n) ? cnt[i] : 0;
    buf[0][tid] = v;
    __syncthreads();
    int pb = 0;
    for (int off = 1; off < 1024; off <<= 1) {
        int t = buf[pb][tid];
        if (tid >= off) t += buf[pb][tid - off];
        buf[1 - pb][tid] = t;
        pb = 1 - pb;
        __syncthreads();
    }
    int incl = buf[pb][tid];
    if (i < n) row_ptr[i] = incl - v;       // block-local exclusive
    if (tid == 1023) partial[blockIdx.x] = incl;
}

__global__ void k_scan2(int* partial, int nb, int* totalp) {
    int l = threadIdx.x;                     // 64 threads, nb <= 64
    int v = (l < nb) ? partial[l] : 0;
    int orig = v;
    for (int off = 1; off < 64; off <<= 1) {
        int t = __shfl_up(v, off);
        if (l >= off) v += t;
    }
    if (l < nb) partial[l] = v - orig;       // exclusive
    if (l == nb - 1) *totalp = v;            // row_ptr[N] = E
}

__global__ void k_scan3(int* row_ptr, int* cursor, const int* __restrict__ partial, int n) {
    int i = blockIdx.x * blockDim.x + threadIdx.x;
    if (i < n) {
        int v = row_ptr[i] + partial[i >> 10];
        row_ptr[i] = v;
        cursor[i] = v;
    }
}

// ---------------- scatter to CSR ----------------
// cv.x = src * 512 (byte offset of bf16 row); cv.y = val bits.

__global__ void k_scatter(const int* __restrict__ src, const int* __restrict__ dst,
                          const float* __restrict__ ea,
                          const float* __restrict__ dinv,
                          int* cursor, int2* cv, int E) {
    int e = blockIdx.x * blockDim.x + threadIdx.x;
    if (e < E) {
        int d = dst[e];
        int s = src[e];
        int p = atomicAdd(&cursor[d], 1);
        cv[p] = make_int2(s << 9, __float_as_int(ea[e] * dinv[s]));  // dinv[dst] factored out per-row
    }
}

// ---------------- W repack fp32 -> bf16 MFMA B-fragment order (all 3 weights) ----------------
__global__ void k_repack3(const float* __restrict__ W1, const float* __restrict__ W2,
                          const float* __restrict__ W3, unsigned short* __restrict__ Wp) {
    int tid = blockIdx.x * blockDim.x + threadIdx.x;  // 3 * 65536
    int w = tid >> 16;
    int t = tid & 65535;
    const float* W = (w == 0) ? W1 : ((w == 1) ? W2 : W3);
    int j = t & 7;
    int l = (t >> 3) & 63;
    int c = (t >> 9) & 15;
    int s = t >> 13;
    int k = s * 32 + ((l >> 4) * 8) + j;
    int n = c * 16 + (l & 15);
    Wp[tid] = f2bf(W[k * 256 + n]);
}

// ---------------- x fp32 -> bf16 cast ----------------
__global__ void k_xcast(const float* __restrict__ x, unsigned short* __restrict__ Xb, int n4) {
    int i = blockIdx.x * blockDim.x + threadIdx.x;
    if (i < n4) {
        float4 v = ((const float4*)x)[i];
        ((ushort4*)Xb)[i] = make_ushort4(f2bf(v.x), f2bf(v.y), f2bf(v.z), f2bf(v.w));
    }
}

// ---------------- XCD-sliced aggregation ----------------
// S[n] = dinv[n]*sum_e val*h[col] + dinv^2*h[n], bf16 in/out.
// slice = blockIdx.x & 7: consecutive blockIdx round-robin across the 8 XCDs
// (perf heuristic only — work is complete/disjoint for ANY block->XCD mapping).
// Each XCD then only gathers its 32-col slice: working set 50000*64B = 3.2MB,
// fits the 4MB per-XCD L2 -> random gathers become L2 hits; HBM misses are
// compulsory (table 25.6MB total) + streamed cv (8x6.4MB).
// Wave: 1 row; 8 edge slots (slot=lane>>3) x 8 lanes x 4 cols (8B loads);
// 2-deep unroll (16 edges in flight/wave); 32-bit voffset addressing.
__global__ __launch_bounds__(256) void k_agg_x8(const unsigned short* __restrict__ Hb,
                                                const int* __restrict__ rowptr,
                                                const int2* __restrict__ cv,
                                                const float* __restrict__ dinv,
                                                unsigned short* __restrict__ S,
                                                int M) {
    int slice = blockIdx.x & 7;
    int rb    = blockIdx.x >> 3;
    int wave  = threadIdx.x >> 6;
    int lane  = threadIdx.x & 63;
    int slot  = lane >> 3;                      // edge slot 0..7
    int l8    = lane & 7;                       // lane within edge
    int n = rb * 4 + wave;
    if (n >= M) return;
    unsigned int cb = (unsigned int)(slice * 64 + l8 * 8);   // byte offset within 512B row
    const char* Hc = (const char*)Hb;

    float a0 = 0.f, a1 = 0.f, a2 = 0.f, a3 = 0.f;
    int e0 = rowptr[n], e1 = rowptr[n + 1];

    int e = e0 + slot;
    for (; e + 8 < e1; e += 16) {
        int2 pA = cv[e];
        int2 pB = cv[e + 8];
        ushort4 hA = *(const ushort4*)(Hc + ((unsigned int)pA.x + cb));
        ushort4 hB = *(const ushort4*)(Hc + ((unsigned int)pB.x + cb));
        float vA = __int_as_float(pA.y);
        float vB = __int_as_float(pB.y);
        a0 = fmaf(vA, bf2f(hA.x), a0); a1 = fmaf(vA, bf2f(hA.y), a1);
        a2 = fmaf(vA, bf2f(hA.z), a2); a3 = fmaf(vA, bf2f(hA.w), a3);
        a0 = fmaf(vB, bf2f(hB.x), a0); a1 = fmaf(vB, bf2f(hB.y), a1);
        a2 = fmaf(vB, bf2f(hB.z), a2); a3 = fmaf(vB, bf2f(hB.w), a3);
    }
    if (e < e1) {
        int2 p = cv[e];
        ushort4 h = *(const ushort4*)(Hc + ((unsigned int)p.x + cb));
        float v = __int_as_float(p.y);
        a0 = fmaf(v, bf2f(h.x), a0); a1 = fmaf(v, bf2f(h.y), a1);
        a2 = fmaf(v, bf2f(h.z), a2); a3 = fmaf(v, bf2f(h.w), a3);
    }
    // reduce the 8 edge slots (lane bits 3,4,5)
    a0 += __shfl_xor(a0, 8); a0 += __shfl_xor(a0, 16); a0 += __shfl_xor(a0, 32);
    a1 += __shfl_xor(a1, 8); a1 += __shfl_xor(a1, 16); a1 += __shfl_xor(a1, 32);
    a2 += __shfl_xor(a2, 8); a2 += __shfl_xor(a2, 16); a2 += __shfl_xor(a2, 32);
    a3 += __shfl_xor(a3, 8); a3 += __shfl_xor(a3, 16); a3 += __shfl_xor(a3, 32);

    if (slot == 0) {
        float di = dinv[n];
        float sc = di * di;
        unsigned int rowb = ((unsigned int)n << 9) + cb;
        ushort4 hn = *(const ushort4*)(Hc + rowb);
        *(ushort4*)((char*)S + rowb) =
            make_ushort4(f2bf(fmaf(di, a0, sc * bf2f(hn.x))),
                         f2bf(fmaf(di, a1, sc * bf2f(hn.y))),
                         f2bf(fmaf(di, a2, sc * bf2f(hn.z))),
                         f2bf(fmaf(di, a3, sc * bf2f(hn.w))));
    }
}

// ---------------- fp32-gather fallback (used only if workspace too small) ----------------
template<bool RELU>
__global__ __launch_bounds__(256) void k_agg(const float* __restrict__ H,
                                             const int* __restrict__ rowptr,
                                             const int2* __restrict__ cv,
                                             const float* __restrict__ dinv,
                                             unsigned short* __restrict__ S, int M) {
    int wave = threadIdx.x >> 6;
    int lane = threadIdx.x & 63;
    int n = blockIdx.x * 4 + wave;
    if (n >= M) return;
    int f4 = lane * 4;

    float a0 = 0.f, a1 = 0.f, a2 = 0.f, a3 = 0.f;
    int e0 = rowptr[n], e1 = rowptr[n + 1];
    for (int e = e0; e < e1; e++) {
        int2 p = cv[e];
        int s = p.x >> 9;                     // decode row index
        float v = __int_as_float(p.y);
        float4 h = *(const float4*)(H + (size_t)s * 256 + f4);
        if (RELU) {
            h.x = fmaxf(h.x, 0.f); h.y = fmaxf(h.y, 0.f);
            h.z = fmaxf(h.z, 0.f); h.w = fmaxf(h.w, 0.f);
        }
        a0 = fmaf(v, h.x, a0); a1 = fmaf(v, h.y, a1);
        a2 = fmaf(v, h.z, a2); a3 = fmaf(v, h.w, a3);
    }
    float di = dinv[n];
    float sc = di * di;
    float4 hn = *(const float4*)(H + (size_t)n * 256 + f4);
    if (RELU) {
        hn.x = fmaxf(hn.x, 0.f); hn.y = fmaxf(hn.y, 0.f);
        hn.z = fmaxf(hn.z, 0.f); hn.w = fmaxf(hn.w, 0.f);
    }
    *(ushort4*)(S + (size_t)n * 256 + f4) =
        make_ushort4(f2bf(fmaf(di, a0, sc * hn.x)), f2bf(fmaf(di, a1, sc * hn.y)),
                     f2bf(fmaf(di, a2, sc * hn.z)), f2bf(fmaf(di, a3, sc * hn.w)));
}

// ---------------- MFMA GEMM: C[M,256] = S[M,256](bf16) @ W + bias ----------------
// W in registers per wave; grid-stride over 16-row tiles. NT: nontemporal C store
// (c1/c2 never re-read in-graph -> keep L2 clean for gather table).
template<bool NT>
__global__ __launch_bounds__(256, 2) void k_gemm2(const unsigned short* __restrict__ S,
                                                  const unsigned short* __restrict__ Wp,
                                                  const float* __restrict__ bias,
                                                  float* __restrict__ C,
                                                  unsigned short* __restrict__ Hb,
                                                  int nTiles) {
    int wave = threadIdx.x >> 6;
    int lane = threadIdx.x & 63;
    int q    = lane >> 4;
    int m16  = lane & 15;
    const short8* wp8 = (const short8*)Wp;

    short8 b[8][4];
#pragma unroll
    for (int s = 0; s < 8; s++)
#pragma unroll
        for (int cc = 0; cc < 4; cc++)
            b[s][cc] = wp8[(s * 16 + wave * 4 + cc) * 64 + lane];

    float bv[4];
#pragma unroll
    for (int cc = 0; cc < 4; cc++) bv[cc] = bias[(wave * 4 + cc) * 16 + m16];

#pragma unroll 1
    for (int rt = blockIdx.x; rt < nTiles; rt += gridDim.x) {
        int arow = rt * 16 + m16;
        short8 a[8];
#pragma unroll
        for (int s = 0; s < 8; s++)
            a[s] = *(const short8*)(S + (size_t)arow * 256 + s * 32 + q * 8);

        f32x4 acc[4];
#pragma unroll
        for (int cc = 0; cc < 4; cc++) acc[cc] = (f32x4){0.f, 0.f, 0.f, 0.f};

#pragma unroll
        for (int s = 0; s < 8; s++)
#pragma unroll
            for (int cc = 0; cc < 4; cc++)
                acc[cc] = __builtin_amdgcn_mfma_f32_16x16x32_bf16(a[s], b[s][cc], acc[cc], 0, 0, 0);

        // C/D layout: col = lane&15, row = (lane>>4)*4 + reg
        int orow0 = rt * 16 + q * 4;
#pragma unroll
        for (int cc = 0; cc < 4; cc++) {
            int colv = (wave * 4 + cc) * 16 + m16;
#pragma unroll
            for (int r = 0; r < 4; r++) {
                float ov = acc[cc][r] + bv[cc];
                if (NT) __builtin_nontemporal_store(ov, &C[(size_t)(orow0 + r) * 256 + colv]);
                else    C[(size_t)(orow0 + r) * 256 + colv] = ov;
            }
        }
        if (Hb != nullptr) {
#pragma unroll
            for (int cc = 0; cc < 4; cc++) {
                int colv = (wave * 4 + cc) * 16 + m16;
#pragma unroll
                for (int r = 0; r < 4; r++)
                    Hb[(size_t)(orow0 + r) * 256 + colv] = f2bf(fmaxf(acc[cc][r] + bv[cc], 0.f));
            }
        }
    }
}

// ---------------- mean pool per graph over relu(c3) (batch sorted) ----------------
__global__ __launch_bounds__(1024) void k_pool(const float* __restrict__ C3,
                                               const int* __restrict__ batch, int N,
                                               float* __restrict__ pooled) {
    int g = blockIdx.x;
    __shared__ int range[2];
    __shared__ float part[4][256];
    if (threadIdx.x == 0 && threadIdx.y == 0) {
        int lo = 0, hi = N;
        while (lo < hi) { int mid = (lo + hi) >> 1; if (batch[mid] < g) lo = mid + 1; else hi = mid; }
        range[0] = lo;
        int lo2 = lo, hi2 = N;
        while (lo2 < hi2) { int mid = (lo2 + hi2) >> 1; if (batch[mid] < g + 1) lo2 = mid + 1; else hi2 = mid; }
        range[1] = lo2;
    }
    __syncthreads();
    int start = range[0], end = range[1];
    int f = threadIdx.x;
    float s = 0.f;
    for (int i = start + threadIdx.y; i < end; i += 4)
        s += fmaxf(C3[(size_t)i * 256 + f], 0.f);
    part[threadIdx.y][f] = s;
    __syncthreads();
    if (threadIdx.y == 0) {
        float tot = part[0][f] + part[1][f] + part[2][f] + part[3][f];
        int cnt = end - start;
        pooled[g * 256 + f] = tot / (float)(cnt > 0 ? cnt : 1);
    }
}

// ---------------- tiny MLP head: 256 -> 64 -> 32 -> 2, relu each ----------------
__global__ __launch_bounds__(64) void k_mlp(const float* __restrict__ pooled,
                                            const float* __restrict__ L1w,
                                            const float* __restrict__ L1b,
                                            const float* __restrict__ L2w,
                                            const float* __restrict__ L2b,
                                            const float* __restrict__ L3w,
                                            const float* __restrict__ L3b,
                                            float* __restrict__ out) {
    int g = blockIdx.x;
    int j = threadIdx.x;
    __shared__ float o1[64];
    __shared__ float o2[32];
    float s = L1b[j];
    const float* p = pooled + g * 256;
    for (int k = 0; k < 256; k++) s = fmaf(p[k], L1w[k * 64 + j], s);
    o1[j] = fmaxf(s, 0.f);
    __syncthreads();
    if (j < 32) {
        float s2 = L2b[j];
        for (int k = 0; k < 64; k++) s2 = fmaf(o1[k], L2w[k * 32 + j], s2);
        o2[j] = fmaxf(s2, 0.f);
    }
    __syncthreads();
    if (j < 2) {
        float s3 = L3b[j];
        for (int k = 0; k < 32; k++) s3 = fmaf(o2[k], L3w[k * 2 + j], s3);
        out[g * 2 + j] = fmaxf(s3, 0.f);
    }
}

extern "C" void kernel_launch(void* const* d_in, const int* in_sizes, int n_in,
                              void* d_out, int out_size, void* d_ws, size_t ws_size,
                              hipStream_t stream) {
    const float* x   = (const float*)d_in[0];
    const int*   ei  = (const int*)d_in[1];
    const float* ea  = (const float*)d_in[2];
    const int*   bat = (const int*)d_in[3];
    const float* W1  = (const float*)d_in[4];
    const float* b1  = (const float*)d_in[5];
    const float* W2  = (const float*)d_in[6];
    const float* b2  = (const float*)d_in[7];
    const float* W3  = (const float*)d_in[8];
    const float* b3  = (const float*)d_in[9];
    const float* L1w = (const float*)d_in[10];
    const float* L1b = (const float*)d_in[11];
    const float* L2w = (const float*)d_in[12];
    const float* L2b = (const float*)d_in[13];
    const float* L3w = (const float*)d_in[14];
    const float* L3b = (const float*)d_in[15];

    const int N = N_NODES, E = N_EDGES;
    const int* srcp = ei;
    const int* dstp = ei + E;

    // d_out layout (fp32 elements): out[256] | pooled[32768] | c1 | c2 | c3
    float* out_p    = (float*)d_out;
    float* pooled_p = out_p + 256;
    float* c1_p     = out_p + 33024;
    float* c2_p     = c1_p + (size_t)N * FDIM;
    float* c3_p     = c2_p + (size_t)N * FDIM;

    // workspace carve (bytes)
    char* ws = (char*)d_ws;
    size_t off = 0;
    unsigned short* Sb  = (unsigned short*)(ws + off); off += (size_t)(N + 64) * FDIM * 2;  // 25.6 MB
    unsigned short* Wp1 = (unsigned short*)(ws + off); off += 65536 * 2;
    unsigned short* Wp2 = (unsigned short*)(ws + off); off += 65536 * 2;
    unsigned short* Wp3 = (unsigned short*)(ws + off); off += 65536 * 2;
    float* dinv    = (float*)(ws + off); off += (size_t)N * 4;
    float* deg     = (float*)(ws + off); off += (size_t)N * 4;
    int*   cnt     = (int*)(ws + off);   off += (size_t)N * 4;
    int*   row_ptr = (int*)(ws + off);   off += ((size_t)N + 16) * 4;
    int*   cursor  = (int*)(ws + off);   off += (size_t)N * 4;
    int2*  cv      = (int2*)(ws + off);  off += (size_t)E * 8;
    int*   partial = (int*)(ws + off);   off += 64 * 4;
    // bf16 gather buffer (x-cast, then relu(c1)/relu(c2) from GEMM epilogue)
    unsigned short* Hb = (unsigned short*)(ws + off); off += (size_t)(N + 64) * FDIM * 2;
    bool use_bf = (ws_size >= off);
    (void)n_in; (void)in_sizes; (void)out_size;

    int nb256 = (N + 255) / 256;
    int eb256 = (E + 255) / 256;
    int nb1024 = (N + 1023) / 1024;          // 49 scan blocks

    k_zero<<<nb256, 256, 0, stream>>>(deg, cnt, N);
    k_deg<<<eb256, 256, 0, stream>>>(dstp, ea, deg, cnt, E);
    k_scan1<<<nb1024, 1024, 0, stream>>>(cnt, deg, dinv, row_ptr, partial, N);
    k_scan2<<<1, 64, 0, stream>>>(partial, nb1024, row_ptr + N);
    k_scan3<<<nb256, 256, 0, stream>>>(row_ptr, cursor, partial, N);
    k_scatter<<<eb256, 256, 0, stream>>>(srcp, dstp, ea, dinv, cursor, cv, E);
    k_repack3<<<768, 256, 0, stream>>>(W1, W2, W3, Wp1);

    int rowBlocks   = (N + 3) / 4;           // 12500
    int agg_grid    = rowBlocks * 8;         // 8 XCD-matched col-slices
    int nTiles      = (N + 15) / 16;         // 3125
    int gemm_blocks = 512;                   // 2 blocks/CU resident, grid-stride

    if (use_bf) {
        k_xcast<<<(N * 64 + 255) / 256, 256, 0, stream>>>(x, Hb, N * 64);
        // layer 1
        k_agg_x8<<<agg_grid, 256, 0, stream>>>(Hb, row_ptr, cv, dinv, Sb, N);
        k_gemm2<true><<<gemm_blocks, 256, 0, stream>>>(Sb, Wp1, b1, c1_p, Hb, nTiles);
        // layer 2
        k_agg_x8<<<agg_grid, 256, 0, stream>>>(Hb, row_ptr, cv, dinv, Sb, N);
        k_gemm2<true><<<gemm_blocks, 256, 0, stream>>>(Sb, Wp2, b2, c2_p, Hb, nTiles);
        // layer 3
        k_agg_x8<<<agg_grid, 256, 0, stream>>>(Hb, row_ptr, cv, dinv, Sb, N);
        k_gemm2<false><<<gemm_blocks, 256, 0, stream>>>(Sb, Wp3, b3, c3_p, nullptr, nTiles);
    } else {
        // fp32-gather fallback (workspace too small for Hb)
        int agg_blocks = (N + 3) / 4;
        k_agg<false><<<agg_blocks, 256, 0, stream>>>(x, row_ptr, cv, dinv, Sb, N);
        k_gemm2<false><<<gemm_blocks, 256, 0, stream>>>(Sb, Wp1, b1, c1_p, nullptr, nTiles);
        k_agg<true><<<agg_blocks, 256, 0, stream>>>(c1_p, row_ptr, cv, dinv, Sb, N);
        k_gemm2<false><<<gemm_blocks, 256, 0, stream>>>(Sb, Wp2, b2, c2_p, nullptr, nTiles);
        k_agg<true><<<agg_blocks, 256, 0, stream>>>(c2_p, row_ptr, cv, dinv, Sb, N);
        k_gemm2<false><<<gemm_blocks, 256, 0, stream>>>(Sb, Wp3, b3, c3_p, nullptr, nTiles);
    }

    // pool + head
    dim3 pb(256, 4);
    k_pool<<<N_GRAPHS, pb, 0, stream>>>(c3_p, bat, N, pooled_p);
    k_mlp<<<N_GRAPHS, 64, 0, stream>>>(pooled_p, L1w, L1b, L2w, L2b, L3w, L3b, out_p);
}

// Round 5
// 786.182 us; speedup vs baseline: 1.0965x; 1.0965x over previous
//
#include <hip/hip_runtime.h>

#define N_NODES  50000
#define N_EDGES  800000
#define N_GRAPHS 128
#define FDIM     256

typedef __attribute__((ext_vector_type(8))) short short8;
typedef __attribute__((ext_vector_type(4))) float f32x4;

__device__ __forceinline__ unsigned short f2bf(float f) {
    union { float f; unsigned int u; } v; v.f = f;
    unsigned int x = v.u;
    unsigned int r = (x + 0x7FFFu + ((x >> 16) & 1u)) >> 16;
    return (unsigned short)r;
}

__device__ __forceinline__ float bf2f(unsigned short u) {
    union { unsigned int i; float f; } v;
    v.i = ((unsigned int)u) << 16;
    return v.f;
}

// ---------------- degree build ----------------

__global__ void k_zero(float* deg, int* cnt, int n) {
    int i = blockIdx.x * blockDim.x + threadIdx.x;
    if (i < n) { deg[i] = 0.0f; cnt[i] = 0; }
}

__global__ void k_deg(const int* __restrict__ dst, const float* __restrict__ ea,
                      float* deg, int* cnt, int E) {
    int e = blockIdx.x * blockDim.x + threadIdx.x;
    if (e < E) {
        int d = dst[e];
        atomicAdd(&deg[d], ea[e]);
        atomicAdd(&cnt[d], 1);
    }
}

// ---------------- 3-phase exclusive scan (dinv folded into phase 1) ----------------

__global__ __launch_bounds__(1024) void k_scan1(const int* __restrict__ cnt,
                                                const float* __restrict__ deg,
                                                float* __restrict__ dinv,
                                                int* row_ptr, int* partial, int n) {
    __shared__ int buf[2][1024];
    int tid = threadIdx.x;
    int i = blockIdx.x * 1024 + tid;
    if (i < n) dinv[i] = rsqrtf(deg[i] + 1.0f);
    int v = (i < n) ? cnt[i] : 0;
    buf[0][tid] = v;
    __syncthreads();
    int pb = 0;
    for (int off = 1; off < 1024; off <<= 1) {
        int t = buf[pb][tid];
        if (tid >= off) t += buf[pb][tid - off];
        buf[1 - pb][tid] = t;
        pb = 1 - pb;
        __syncthreads();
    }
    int incl = buf[pb][tid];
    if (i < n) row_ptr[i] = incl - v;       // block-local exclusive
    if (tid == 1023) partial[blockIdx.x] = incl;
}

__global__ void k_scan2(int* partial, int nb, int* totalp) {
    int l = threadIdx.x;                     // 64 threads, nb <= 64
    int v = (l < nb) ? partial[l] : 0;
    int orig = v;
    for (int off = 1; off < 64; off <<= 1) {
        int t = __shfl_up(v, off);
        if (l >= off) v += t;
    }
    if (l < nb) partial[l] = v - orig;       // exclusive
    if (l == nb - 1) *totalp = v;            // row_ptr[N] = E
}

__global__ void k_scan3(int* row_ptr, int* cursor, const int* __restrict__ partial, int n) {
    int i = blockIdx.x * blockDim.x + threadIdx.x;
    if (i < n) {
        int v = row_ptr[i] + partial[i >> 10];
        row_ptr[i] = v;
        cursor[i] = v;
    }
}

// ---------------- scatter to CSR ----------------
// cv.x = src * 512 (byte offset of bf16 row); cv.y = val bits.

__global__ void k_scatter(const int* __restrict__ src, const int* __restrict__ dst,
                          const float* __restrict__ ea,
                          const float* __restrict__ dinv,
                          int* cursor, int2* cv, int E) {
    int e = blockIdx.x * blockDim.x + threadIdx.x;
    if (e < E) {
        int d = dst[e];
        int s = src[e];
        int p = atomicAdd(&cursor[d], 1);
        cv[p] = make_int2(s << 9, __float_as_int(ea[e] * dinv[s]));  // dinv[dst] factored out per-row
    }
}

// ---------------- W repack fp32 -> bf16 MFMA B-fragment order (all 3 weights) ----------------
__global__ void k_repack3(const float* __restrict__ W1, const float* __restrict__ W2,
                          const float* __restrict__ W3, unsigned short* __restrict__ Wp) {
    int tid = blockIdx.x * blockDim.x + threadIdx.x;  // 3 * 65536
    int w = tid >> 16;
    int t = tid & 65535;
    const float* W = (w == 0) ? W1 : ((w == 1) ? W2 : W3);
    int j = t & 7;
    int l = (t >> 3) & 63;
    int c = (t >> 9) & 15;
    int s = t >> 13;
    int k = s * 32 + ((l >> 4) * 8) + j;
    int n = c * 16 + (l & 15);
    Wp[tid] = f2bf(W[k * 256 + n]);
}

// ---------------- x fp32 -> bf16 cast ----------------
__global__ void k_xcast(const float* __restrict__ x, unsigned short* __restrict__ Xb, int n4) {
    int i = blockIdx.x * blockDim.x + threadIdx.x;
    if (i < n4) {
        float4 v = ((const float4*)x)[i];
        ((ushort4*)Xb)[i] = make_ushort4(f2bf(v.x), f2bf(v.y), f2bf(v.z), f2bf(v.w));
    }
}

// ---------------- FUSED layer: agg(16-row tile) -> LDS -> MFMA GEMM -> C (+HbOut) ----------------
// Agg (round-1 structure, the only one measured to saturate ~6.3TB/s): 1 wave per
// row, lane covers 4 cols (8B loads), full 512B row per edge, 4 edges in flight.
// S tile in LDS (row stride 264 shorts = 528B -> 4-bank row skew, <=2-way conflict).
// GEMM: W in registers per wave (4 col-tiles); grid-stride over 16-row tiles.
// HbIn (gather table) and HbOut (next layer's table) MUST be distinct buffers:
// blocks run concurrently, epilogue writes must not clobber rows other blocks
// still gather (ping-pong at launch level).
template<bool NT, bool EMIT_HB>
__global__ __launch_bounds__(256, 2) void k_fused(const unsigned short* __restrict__ HbIn,
                                                  const int* __restrict__ rowptr,
                                                  const int2* __restrict__ cv,
                                                  const float* __restrict__ dinv,
                                                  const unsigned short* __restrict__ Wp,
                                                  const float* __restrict__ bias,
                                                  float* __restrict__ C,
                                                  unsigned short* __restrict__ HbOut,
                                                  int nTiles) {
    __shared__ unsigned short S_lds[16][264];
    int wave = threadIdx.x >> 6;
    int lane = threadIdx.x & 63;
    int q    = lane >> 4;
    int m16  = lane & 15;
    const short8* wp8 = (const short8*)Wp;
    const char* Hc = (const char*)HbIn;

    short8 b[8][4];
#pragma unroll
    for (int s = 0; s < 8; s++)
#pragma unroll
        for (int cc = 0; cc < 4; cc++)
            b[s][cc] = wp8[(s * 16 + wave * 4 + cc) * 64 + lane];

    float bv[4];
#pragma unroll
    for (int cc = 0; cc < 4; cc++) bv[cc] = bias[(wave * 4 + cc) * 16 + m16];

    unsigned int cb2 = (unsigned int)(lane * 8);   // lane's byte offset within a 512B row

#pragma unroll 1
    for (int rt = blockIdx.x; rt < nTiles; rt += gridDim.x) {
        // ---------- agg phase: wave w aggregates local rows w*4 .. w*4+3 ----------
#pragma unroll 1
        for (int rr = 0; rr < 4; rr++) {
            int n = rt * 16 + wave * 4 + rr;             // nTiles*16 == N exactly
            float a0 = 0.f, a1 = 0.f, a2 = 0.f, a3 = 0.f;
            int e0 = rowptr[n], e1 = rowptr[n + 1];
            int e = e0;
#pragma unroll 1
            for (; e + 4 <= e1; e += 4) {
                int2 p0 = cv[e], p1 = cv[e + 1], p2 = cv[e + 2], p3 = cv[e + 3];
                ushort4 h0 = *(const ushort4*)(Hc + ((unsigned int)p0.x + cb2));
                ushort4 h1 = *(const ushort4*)(Hc + ((unsigned int)p1.x + cb2));
                ushort4 h2 = *(const ushort4*)(Hc + ((unsigned int)p2.x + cb2));
                ushort4 h3 = *(const ushort4*)(Hc + ((unsigned int)p3.x + cb2));
                float v0 = __int_as_float(p0.y), v1 = __int_as_float(p1.y);
                float v2 = __int_as_float(p2.y), v3 = __int_as_float(p3.y);
                a0 = fmaf(v0, bf2f(h0.x), a0); a1 = fmaf(v0, bf2f(h0.y), a1);
                a2 = fmaf(v0, bf2f(h0.z), a2); a3 = fmaf(v0, bf2f(h0.w), a3);
                a0 = fmaf(v1, bf2f(h1.x), a0); a1 = fmaf(v1, bf2f(h1.y), a1);
                a2 = fmaf(v1, bf2f(h1.z), a2); a3 = fmaf(v1, bf2f(h1.w), a3);
                a0 = fmaf(v2, bf2f(h2.x), a0); a1 = fmaf(v2, bf2f(h2.y), a1);
                a2 = fmaf(v2, bf2f(h2.z), a2); a3 = fmaf(v2, bf2f(h2.w), a3);
                a0 = fmaf(v3, bf2f(h3.x), a0); a1 = fmaf(v3, bf2f(h3.y), a1);
                a2 = fmaf(v3, bf2f(h3.z), a2); a3 = fmaf(v3, bf2f(h3.w), a3);
            }
#pragma unroll 1
            for (; e < e1; e++) {
                int2 p = cv[e];
                ushort4 h = *(const ushort4*)(Hc + ((unsigned int)p.x + cb2));
                float v = __int_as_float(p.y);
                a0 = fmaf(v, bf2f(h.x), a0); a1 = fmaf(v, bf2f(h.y), a1);
                a2 = fmaf(v, bf2f(h.z), a2); a3 = fmaf(v, bf2f(h.w), a3);
            }
            float di = dinv[n];
            float sc = di * di;
            ushort4 hn = *(const ushort4*)(Hc + (((unsigned int)n << 9) + cb2));
            *(ushort4*)(&S_lds[wave * 4 + rr][lane * 4]) =
                make_ushort4(f2bf(fmaf(di, a0, sc * bf2f(hn.x))),
                             f2bf(fmaf(di, a1, sc * bf2f(hn.y))),
                             f2bf(fmaf(di, a2, sc * bf2f(hn.z))),
                             f2bf(fmaf(di, a3, sc * bf2f(hn.w))));
        }
        __syncthreads();

        // ---------- gemm phase ----------
        short8 a[8];
#pragma unroll
        for (int s = 0; s < 8; s++)
            a[s] = *(const short8*)(&S_lds[m16][s * 32 + q * 8]);

        f32x4 acc[4];
#pragma unroll
        for (int cc = 0; cc < 4; cc++) acc[cc] = (f32x4){0.f, 0.f, 0.f, 0.f};

#pragma unroll
        for (int s = 0; s < 8; s++)
#pragma unroll
            for (int cc = 0; cc < 4; cc++)
                acc[cc] = __builtin_amdgcn_mfma_f32_16x16x32_bf16(a[s], b[s][cc], acc[cc], 0, 0, 0);

        // C/D layout: col = lane&15, row = (lane>>4)*4 + reg
        int orow0 = rt * 16 + q * 4;
#pragma unroll
        for (int cc = 0; cc < 4; cc++) {
            int colv = (wave * 4 + cc) * 16 + m16;
#pragma unroll
            for (int r = 0; r < 4; r++) {
                float ov = acc[cc][r] + bv[cc];
                if (NT) __builtin_nontemporal_store(ov, &C[(size_t)(orow0 + r) * 256 + colv]);
                else    C[(size_t)(orow0 + r) * 256 + colv] = ov;
            }
        }
        if (EMIT_HB) {
#pragma unroll
            for (int cc = 0; cc < 4; cc++) {
                int colv = (wave * 4 + cc) * 16 + m16;
#pragma unroll
                for (int r = 0; r < 4; r++)
                    HbOut[(size_t)(orow0 + r) * 256 + colv] = f2bf(fmaxf(acc[cc][r] + bv[cc], 0.f));
            }
        }
        __syncthreads();    // S_lds reused next tile
    }
}

// ---------------- fp32-gather fallback path (workspace too small for Hb) ----------------
template<bool RELU>
__global__ __launch_bounds__(256) void k_agg(const float* __restrict__ H,
                                             const int* __restrict__ rowptr,
                                             const int2* __restrict__ cv,
                                             const float* __restrict__ dinv,
                                             unsigned short* __restrict__ S, int M) {
    int wave = threadIdx.x >> 6;
    int lane = threadIdx.x & 63;
    int n = blockIdx.x * 4 + wave;
    if (n >= M) return;
    int f4 = lane * 4;

    float a0 = 0.f, a1 = 0.f, a2 = 0.f, a3 = 0.f;
    int e0 = rowptr[n], e1 = rowptr[n + 1];
    for (int e = e0; e < e1; e++) {
        int2 p = cv[e];
        int s = p.x >> 9;                     // decode row index
        float v = __int_as_float(p.y);
        float4 h = *(const float4*)(H + (size_t)s * 256 + f4);
        if (RELU) {
            h.x = fmaxf(h.x, 0.f); h.y = fmaxf(h.y, 0.f);
            h.z = fmaxf(h.z, 0.f); h.w = fmaxf(h.w, 0.f);
        }
        a0 = fmaf(v, h.x, a0); a1 = fmaf(v, h.y, a1);
        a2 = fmaf(v, h.z, a2); a3 = fmaf(v, h.w, a3);
    }
    float di = dinv[n];
    float sc = di * di;
    float4 hn = *(const float4*)(H + (size_t)n * 256 + f4);
    if (RELU) {
        hn.x = fmaxf(hn.x, 0.f); hn.y = fmaxf(hn.y, 0.f);
        hn.z = fmaxf(hn.z, 0.f); hn.w = fmaxf(hn.w, 0.f);
    }
    *(ushort4*)(S + (size_t)n * 256 + f4) =
        make_ushort4(f2bf(fmaf(di, a0, sc * hn.x)), f2bf(fmaf(di, a1, sc * hn.y)),
                     f2bf(fmaf(di, a2, sc * hn.z)), f2bf(fmaf(di, a3, sc * hn.w)));
}

__global__ __launch_bounds__(256, 2) void k_gemm2(const unsigned short* __restrict__ S,
                                                  const unsigned short* __restrict__ Wp,
                                                  const float* __restrict__ bias,
                                                  float* __restrict__ C,
                                                  int nTiles) {
    int wave = threadIdx.x >> 6;
    int lane = threadIdx.x & 63;
    int q    = lane >> 4;
    int m16  = lane & 15;
    const short8* wp8 = (const short8*)Wp;

    short8 b[8][4];
#pragma unroll
    for (int s = 0; s < 8; s++)
#pragma unroll
        for (int cc = 0; cc < 4; cc++)
            b[s][cc] = wp8[(s * 16 + wave * 4 + cc) * 64 + lane];

    float bv[4];
#pragma unroll
    for (int cc = 0; cc < 4; cc++) bv[cc] = bias[(wave * 4 + cc) * 16 + m16];

#pragma unroll 1
    for (int rt = blockIdx.x; rt < nTiles; rt += gridDim.x) {
        int arow = rt * 16 + m16;
        short8 a[8];
#pragma unroll
        for (int s = 0; s < 8; s++)
            a[s] = *(const short8*)(S + (size_t)arow * 256 + s * 32 + q * 8);

        f32x4 acc[4];
#pragma unroll
        for (int cc = 0; cc < 4; cc++) acc[cc] = (f32x4){0.f, 0.f, 0.f, 0.f};

#pragma unroll
        for (int s = 0; s < 8; s++)
#pragma unroll
            for (int cc = 0; cc < 4; cc++)
                acc[cc] = __builtin_amdgcn_mfma_f32_16x16x32_bf16(a[s], b[s][cc], acc[cc], 0, 0, 0);

        int orow0 = rt * 16 + q * 4;
#pragma unroll
        for (int cc = 0; cc < 4; cc++) {
            int colv = (wave * 4 + cc) * 16 + m16;
#pragma unroll
            for (int r = 0; r < 4; r++)
                C[(size_t)(orow0 + r) * 256 + colv] = acc[cc][r] + bv[cc];
        }
    }
}

// ---------------- mean pool per graph over relu(c3) (batch sorted) ----------------
__global__ __launch_bounds__(1024) void k_pool(const float* __restrict__ C3,
                                               const int* __restrict__ batch, int N,
                                               float* __restrict__ pooled) {
    int g = blockIdx.x;
    __shared__ int range[2];
    __shared__ float part[4][256];
    if (threadIdx.x == 0 && threadIdx.y == 0) {
        int lo = 0, hi = N;
        while (lo < hi) { int mid = (lo + hi) >> 1; if (batch[mid] < g) lo = mid + 1; else hi = mid; }
        range[0] = lo;
        int lo2 = lo, hi2 = N;
        while (lo2 < hi2) { int mid = (lo2 + hi2) >> 1; if (batch[mid] < g + 1) lo2 = mid + 1; else hi2 = mid; }
        range[1] = lo2;
    }
    __syncthreads();
    int start = range[0], end = range[1];
    int f = threadIdx.x;
    float s = 0.f;
    for (int i = start + threadIdx.y; i < end; i += 4)
        s += fmaxf(C3[(size_t)i * 256 + f], 0.f);
    part[threadIdx.y][f] = s;
    __syncthreads();
    if (threadIdx.y == 0) {
        float tot = part[0][f] + part[1][f] + part[2][f] + part[3][f];
        int cnt = end - start;
        pooled[g * 256 + f] = tot / (float)(cnt > 0 ? cnt : 1);
    }
}

// ---------------- tiny MLP head: 256 -> 64 -> 32 -> 2, relu each ----------------
__global__ __launch_bounds__(64) void k_mlp(const float* __restrict__ pooled,
                                            const float* __restrict__ L1w,
                                            const float* __restrict__ L1b,
                                            const float* __restrict__ L2w,
                                            const float* __restrict__ L2b,
                                            const float* __restrict__ L3w,
                                            const float* __restrict__ L3b,
                                            float* __restrict__ out) {
    int g = blockIdx.x;
    int j = threadIdx.x;
    __shared__ float o1[64];
    __shared__ float o2[32];
    float s = L1b[j];
    const float* p = pooled + g * 256;
    for (int k = 0; k < 256; k++) s = fmaf(p[k], L1w[k * 64 + j], s);
    o1[j] = fmaxf(s, 0.f);
    __syncthreads();
    if (j < 32) {
        float s2 = L2b[j];
        for (int k = 0; k < 64; k++) s2 = fmaf(o1[k], L2w[k * 32 + j], s2);
        o2[j] = fmaxf(s2, 0.f);
    }
    __syncthreads();
    if (j < 2) {
        float s3 = L3b[j];
        for (int k = 0; k < 32; k++) s3 = fmaf(o2[k], L3w[k * 2 + j], s3);
        out[g * 2 + j] = fmaxf(s3, 0.f);
    }
}

extern "C" void kernel_launch(void* const* d_in, const int* in_sizes, int n_in,
                              void* d_out, int out_size, void* d_ws, size_t ws_size,
                              hipStream_t stream) {
    const float* x   = (const float*)d_in[0];
    const int*   ei  = (const int*)d_in[1];
    const float* ea  = (const float*)d_in[2];
    const int*   bat = (const int*)d_in[3];
    const float* W1  = (const float*)d_in[4];
    const float* b1  = (const float*)d_in[5];
    const float* W2  = (const float*)d_in[6];
    const float* b2  = (const float*)d_in[7];
    const float* W3  = (const float*)d_in[8];
    const float* b3  = (const float*)d_in[9];
    const float* L1w = (const float*)d_in[10];
    const float* L1b = (const float*)d_in[11];
    const float* L2w = (const float*)d_in[12];
    const float* L2b = (const float*)d_in[13];
    const float* L3w = (const float*)d_in[14];
    const float* L3b = (const float*)d_in[15];

    const int N = N_NODES, E = N_EDGES;
    const int* srcp = ei;
    const int* dstp = ei + E;

    // d_out layout (fp32 elements): out[256] | pooled[32768] | c1 | c2 | c3
    float* out_p    = (float*)d_out;
    float* pooled_p = out_p + 256;
    float* c1_p     = out_p + 33024;
    float* c2_p     = c1_p + (size_t)N * FDIM;
    float* c3_p     = c2_p + (size_t)N * FDIM;

    // workspace carve (bytes)
    char* ws = (char*)d_ws;
    size_t off = 0;
    unsigned short* Sb  = (unsigned short*)(ws + off); off += (size_t)(N + 64) * FDIM * 2;  // fallback only
    unsigned short* Wp1 = (unsigned short*)(ws + off); off += 65536 * 2;
    unsigned short* Wp2 = (unsigned short*)(ws + off); off += 65536 * 2;
    unsigned short* Wp3 = (unsigned short*)(ws + off); off += 65536 * 2;
    float* dinv    = (float*)(ws + off); off += (size_t)N * 4;
    float* deg     = (float*)(ws + off); off += (size_t)N * 4;
    int*   cnt     = (int*)(ws + off);   off += (size_t)N * 4;
    int*   row_ptr = (int*)(ws + off);   off += ((size_t)N + 16) * 4;
    int*   cursor  = (int*)(ws + off);   off += (size_t)N * 4;
    int2*  cv      = (int2*)(ws + off);  off += (size_t)E * 8;
    int*   partial = (int*)(ws + off);   off += 64 * 4;
    // ping-pong bf16 gather tables (layer k gathers HbA, epilogue writes HbB, swap)
    unsigned short* HbA = (unsigned short*)(ws + off); off += (size_t)(N + 64) * FDIM * 2;
    unsigned short* HbB = (unsigned short*)(ws + off); off += (size_t)(N + 64) * FDIM * 2;
    bool use_bf = (ws_size >= off);
    (void)n_in; (void)in_sizes; (void)out_size;

    int nb256 = (N + 255) / 256;
    int eb256 = (E + 255) / 256;
    int nb1024 = (N + 1023) / 1024;          // 49 scan blocks

    k_zero<<<nb256, 256, 0, stream>>>(deg, cnt, N);
    k_deg<<<eb256, 256, 0, stream>>>(dstp, ea, deg, cnt, E);
    k_scan1<<<nb1024, 1024, 0, stream>>>(cnt, deg, dinv, row_ptr, partial, N);
    k_scan2<<<1, 64, 0, stream>>>(partial, nb1024, row_ptr + N);
    k_scan3<<<nb256, 256, 0, stream>>>(row_ptr, cursor, partial, N);
    k_scatter<<<eb256, 256, 0, stream>>>(srcp, dstp, ea, dinv, cursor, cv, E);
    k_repack3<<<768, 256, 0, stream>>>(W1, W2, W3, Wp1);

    int nTiles       = N / 16;               // 3125 (N divisible by 16)
    int fused_blocks = 512;                  // 2 blocks/CU resident, grid-stride

    if (use_bf) {
        k_xcast<<<(N * 64 + 255) / 256, 256, 0, stream>>>(x, HbA, N * 64);
        k_fused<true,  true ><<<fused_blocks, 256, 0, stream>>>(HbA, row_ptr, cv, dinv, Wp1, b1, c1_p, HbB, nTiles);
        k_fused<true,  true ><<<fused_blocks, 256, 0, stream>>>(HbB, row_ptr, cv, dinv, Wp2, b2, c2_p, HbA, nTiles);
        k_fused<false, false><<<fused_blocks, 256, 0, stream>>>(HbA, row_ptr, cv, dinv, Wp3, b3, c3_p, HbB, nTiles);
    } else {
        // fp32-gather fallback (workspace too small for ping-pong tables)
        int agg_blocks = (N + 3) / 4;
        k_agg<false><<<agg_blocks, 256, 0, stream>>>(x, row_ptr, cv, dinv, Sb, N);
        k_gemm2<<<fused_blocks, 256, 0, stream>>>(Sb, Wp1, b1, c1_p, nTiles);
        k_agg<true><<<agg_blocks, 256, 0, stream>>>(c1_p, row_ptr, cv, dinv, Sb, N);
        k_gemm2<<<fused_blocks, 256, 0, stream>>>(Sb, Wp2, b2, c2_p, nTiles);
        k_agg<true><<<agg_blocks, 256, 0, stream>>>(c2_p, row_ptr, cv, dinv, Sb, N);
        k_gemm2<<<fused_blocks, 256, 0, stream>>>(Sb, Wp3, b3, c3_p, nTiles);
    }

    // pool + head
    dim3 pb(256, 4);
    k_pool<<<N_GRAPHS, pb, 0, stream>>>(c3_p, bat, N, pooled_p);
    k_mlp<<<N_GRAPHS, 64, 0, stream>>>(pooled_p, L1w, L1b, L2w, L2b, L3w, L3b, out_p);
}

// Round 6
// 605.994 us; speedup vs baseline: 1.4226x; 1.2973x over previous
//
#include <hip/hip_runtime.h>

#define N_NODES  50000
#define N_EDGES  800000
#define N_GRAPHS 128
#define FDIM     256

typedef __attribute__((ext_vector_type(8))) short short8;
typedef __attribute__((ext_vector_type(4))) float f32x4;

__device__ __forceinline__ unsigned short f2bf(float f) {
    union { float f; unsigned int u; } v; v.f = f;
    unsigned int x = v.u;
    unsigned int r = (x + 0x7FFFu + ((x >> 16) & 1u)) >> 16;
    return (unsigned short)r;
}

__device__ __forceinline__ float bf2f(unsigned short u) {
    union { unsigned int i; float f; } v;
    v.i = ((unsigned int)u) << 16;
    return v.f;
}

// ---------------- prep: zero(deg,cnt) + xcast(x->bf16) + repack(W1..3) fused ----------------
// All three are independent elementwise jobs; one launch, ranges by blockIdx.
#define ZBLK 196      // zero: 196*256 >= 50000
#define XBLK 12500    // xcast: 50000*64 f32x4 groups / 256
#define RBLK 768      // repack: 3*65536 / 256

__global__ __launch_bounds__(256) void k_prep(float* __restrict__ deg, int* __restrict__ cnt,
                                              const float* __restrict__ x, unsigned short* __restrict__ Xb,
                                              const float* __restrict__ W1, const float* __restrict__ W2,
                                              const float* __restrict__ W3, unsigned short* __restrict__ Wp) {
    int b = blockIdx.x;
    int tid = threadIdx.x;
    if (b < ZBLK) {
        int i = b * 256 + tid;
        if (i < N_NODES) { deg[i] = 0.0f; cnt[i] = 0; }
    } else if (b < ZBLK + XBLK) {
        int i = (b - ZBLK) * 256 + tid;          // < 3.2M
        float4 v = ((const float4*)x)[i];
        ((ushort4*)Xb)[i] = make_ushort4(f2bf(v.x), f2bf(v.y), f2bf(v.z), f2bf(v.w));
    } else {
        int t3 = (b - ZBLK - XBLK) * 256 + tid;  // < 196608
        int w = t3 >> 16;
        int t = t3 & 65535;
        const float* W = (w == 0) ? W1 : ((w == 1) ? W2 : W3);
        int j = t & 7;
        int l = (t >> 3) & 63;
        int c = (t >> 9) & 15;
        int s = t >> 13;
        int k = s * 32 + ((l >> 4) * 8) + j;
        int n = c * 16 + (l & 15);
        Wp[t3] = f2bf(W[k * 256 + n]);
    }
}

// ---------------- degree build ----------------

__global__ void k_deg(const int* __restrict__ dst, const float* __restrict__ ea,
                      float* deg, int* cnt, int E) {
    int e = blockIdx.x * blockDim.x + threadIdx.x;
    if (e < E) {
        int d = dst[e];
        atomicAdd(&deg[d], ea[e]);
        atomicAdd(&cnt[d], 1);
    }
}

// ---------------- 2-kernel exclusive scan (dinv folded into phase 1) ----------------

__global__ __launch_bounds__(1024) void k_scan1(const int* __restrict__ cnt,
                                                const float* __restrict__ deg,
                                                float* __restrict__ dinv,
                                                int* row_ptr, int* partial, int n) {
    __shared__ int buf[2][1024];
    int tid = threadIdx.x;
    int i = blockIdx.x * 1024 + tid;
    if (i < n) dinv[i] = rsqrtf(deg[i] + 1.0f);
    int v = (i < n) ? cnt[i] : 0;
    buf[0][tid] = v;
    __syncthreads();
    int pb = 0;
    for (int off = 1; off < 1024; off <<= 1) {
        int t = buf[pb][tid];
        if (tid >= off) t += buf[pb][tid - off];
        buf[1 - pb][tid] = t;
        pb = 1 - pb;
        __syncthreads();
    }
    int incl = buf[pb][tid];
    if (i < n) row_ptr[i] = incl - v;       // block-local exclusive
    if (tid == 1023) partial[blockIdx.x] = incl;
}

// Each block redundantly wave-scans the 49 partials (no cross-block dependency),
// then adds the block-prefix and writes row_ptr/cursor.
__global__ __launch_bounds__(256) void k_scan2(int* row_ptr, int* cursor,
                                               const int* __restrict__ partial,
                                               int nb, int n) {
    __shared__ int pre[64];
    int tid = threadIdx.x;
    if (tid < 64) {
        int v = (tid < nb) ? partial[tid] : 0;
        for (int off = 1; off < 64; off <<= 1) {
            int t = __shfl_up(v, off);
            if (tid >= off) v += t;
        }
        pre[tid] = v;                        // inclusive prefix
    }
    __syncthreads();
    int i = blockIdx.x * 256 + tid;
    if (i < n) {
        int b = i >> 10;
        int add = (b > 0) ? pre[b - 1] : 0;
        int v = row_ptr[i] + add;
        row_ptr[i] = v;
        cursor[i] = v;
    }
    if (blockIdx.x == 0 && tid == 0) row_ptr[n] = N_EDGES;
}

// ---------------- scatter to CSR ----------------
// cv.x = src * 512 (byte offset of bf16 row); cv.y = val bits.

__global__ void k_scatter(const int* __restrict__ src, const int* __restrict__ dst,
                          const float* __restrict__ ea,
                          const float* __restrict__ dinv,
                          int* cursor, int2* cv, int E) {
    int e = blockIdx.x * blockDim.x + threadIdx.x;
    if (e < E) {
        int d = dst[e];
        int s = src[e];
        int p = atomicAdd(&cursor[d], 1);
        cv[p] = make_int2(s << 9, __float_as_int(ea[e] * dinv[s]));  // dinv[dst] factored out per-row
    }
}

// ---------------- aggregation (bf16 gather, round-1 structure + 32-bit addressing) ----------------
// S[n] = dinv[n]*sum val*h[col] + dinv^2*h[n]. 1 wave/row, lane covers 4 cols (8B),
// full 512B row per edge, 4 gathers in flight; 12500 blocks -> full occupancy.
__global__ __launch_bounds__(256) void k_agg_bf(const unsigned short* __restrict__ Hb,
                                                const int* __restrict__ rowptr,
                                                const int2* __restrict__ cv,
                                                const float* __restrict__ dinv,
                                                unsigned short* __restrict__ S, int M) {
    int wave = threadIdx.x >> 6;
    int lane = threadIdx.x & 63;
    int n = blockIdx.x * 4 + wave;
    if (n >= M) return;
    unsigned int cb2 = (unsigned int)(lane * 8);       // byte offset within 512B row
    const char* Hc = (const char*)Hb;

    float a0 = 0.f, a1 = 0.f, a2 = 0.f, a3 = 0.f;
    int e0 = rowptr[n], e1 = rowptr[n + 1];
    int e = e0;
#pragma unroll 1
    for (; e + 4 <= e1; e += 4) {
        int2 p0 = cv[e], p1 = cv[e + 1], p2 = cv[e + 2], p3 = cv[e + 3];
        ushort4 h0 = *(const ushort4*)(Hc + ((unsigned int)p0.x + cb2));
        ushort4 h1 = *(const ushort4*)(Hc + ((unsigned int)p1.x + cb2));
        ushort4 h2 = *(const ushort4*)(Hc + ((unsigned int)p2.x + cb2));
        ushort4 h3 = *(const ushort4*)(Hc + ((unsigned int)p3.x + cb2));
        float v0 = __int_as_float(p0.y), v1 = __int_as_float(p1.y);
        float v2 = __int_as_float(p2.y), v3 = __int_as_float(p3.y);
        a0 = fmaf(v0, bf2f(h0.x), a0); a1 = fmaf(v0, bf2f(h0.y), a1);
        a2 = fmaf(v0, bf2f(h0.z), a2); a3 = fmaf(v0, bf2f(h0.w), a3);
        a0 = fmaf(v1, bf2f(h1.x), a0); a1 = fmaf(v1, bf2f(h1.y), a1);
        a2 = fmaf(v1, bf2f(h1.z), a2); a3 = fmaf(v1, bf2f(h1.w), a3);
        a0 = fmaf(v2, bf2f(h2.x), a0); a1 = fmaf(v2, bf2f(h2.y), a1);
        a2 = fmaf(v2, bf2f(h2.z), a2); a3 = fmaf(v2, bf2f(h2.w), a3);
        a0 = fmaf(v3, bf2f(h3.x), a0); a1 = fmaf(v3, bf2f(h3.y), a1);
        a2 = fmaf(v3, bf2f(h3.z), a2); a3 = fmaf(v3, bf2f(h3.w), a3);
    }
#pragma unroll 1
    for (; e < e1; e++) {
        int2 p = cv[e];
        ushort4 h = *(const ushort4*)(Hc + ((unsigned int)p.x + cb2));
        float v = __int_as_float(p.y);
        a0 = fmaf(v, bf2f(h.x), a0); a1 = fmaf(v, bf2f(h.y), a1);
        a2 = fmaf(v, bf2f(h.z), a2); a3 = fmaf(v, bf2f(h.w), a3);
    }
    float di = dinv[n];
    float sc = di * di;
    unsigned int rowb = ((unsigned int)n << 9) + cb2;
    ushort4 hn = *(const ushort4*)(Hc + rowb);
    *(ushort4*)((char*)S + rowb) =
        make_ushort4(f2bf(fmaf(di, a0, sc * bf2f(hn.x))),
                     f2bf(fmaf(di, a1, sc * bf2f(hn.y))),
                     f2bf(fmaf(di, a2, sc * bf2f(hn.z))),
                     f2bf(fmaf(di, a3, sc * bf2f(hn.w))));
}

// ---------------- fp32-gather fallback (workspace too small for Hb) ----------------
template<bool RELU>
__global__ __launch_bounds__(256) void k_agg(const float* __restrict__ H,
                                             const int* __restrict__ rowptr,
                                             const int2* __restrict__ cv,
                                             const float* __restrict__ dinv,
                                             unsigned short* __restrict__ S, int M) {
    int wave = threadIdx.x >> 6;
    int lane = threadIdx.x & 63;
    int n = blockIdx.x * 4 + wave;
    if (n >= M) return;
    int f4 = lane * 4;

    float a0 = 0.f, a1 = 0.f, a2 = 0.f, a3 = 0.f;
    int e0 = rowptr[n], e1 = rowptr[n + 1];
    for (int e = e0; e < e1; e++) {
        int2 p = cv[e];
        int s = p.x >> 9;                     // decode row index
        float v = __int_as_float(p.y);
        float4 h = *(const float4*)(H + (size_t)s * 256 + f4);
        if (RELU) {
            h.x = fmaxf(h.x, 0.f); h.y = fmaxf(h.y, 0.f);
            h.z = fmaxf(h.z, 0.f); h.w = fmaxf(h.w, 0.f);
        }
        a0 = fmaf(v, h.x, a0); a1 = fmaf(v, h.y, a1);
        a2 = fmaf(v, h.z, a2); a3 = fmaf(v, h.w, a3);
    }
    float di = dinv[n];
    float sc = di * di;
    float4 hn = *(const float4*)(H + (size_t)n * 256 + f4);
    if (RELU) {
        hn.x = fmaxf(hn.x, 0.f); hn.y = fmaxf(hn.y, 0.f);
        hn.z = fmaxf(hn.z, 0.f); hn.w = fmaxf(hn.w, 0.f);
    }
    *(ushort4*)(S + (size_t)n * 256 + f4) =
        make_ushort4(f2bf(fmaf(di, a0, sc * hn.x)), f2bf(fmaf(di, a1, sc * hn.y)),
                     f2bf(fmaf(di, a2, sc * hn.z)), f2bf(fmaf(di, a3, sc * hn.w)));
}

// ---------------- MFMA GEMM: C[M,256] = S[M,256](bf16) @ W + bias ----------------
// W in registers per wave (4 col-tiles); grid-stride over 16-row tiles.
// NT: nontemporal C store (c1/c2 never re-read in-graph -> keep L2 for gather table).
// Hb != nullptr: also emit bf16 relu(C) (next layer's gather table).
template<bool NT>
__global__ __launch_bounds__(256, 2) void k_gemm2(const unsigned short* __restrict__ S,
                                                  const unsigned short* __restrict__ Wp,
                                                  const float* __restrict__ bias,
                                                  float* __restrict__ C,
                                                  unsigned short* __restrict__ Hb,
                                                  int nTiles) {
    int wave = threadIdx.x >> 6;
    int lane = threadIdx.x & 63;
    int q    = lane >> 4;
    int m16  = lane & 15;
    const short8* wp8 = (const short8*)Wp;

    short8 b[8][4];
#pragma unroll
    for (int s = 0; s < 8; s++)
#pragma unroll
        for (int cc = 0; cc < 4; cc++)
            b[s][cc] = wp8[(s * 16 + wave * 4 + cc) * 64 + lane];

    float bv[4];
#pragma unroll
    for (int cc = 0; cc < 4; cc++) bv[cc] = bias[(wave * 4 + cc) * 16 + m16];

#pragma unroll 1
    for (int rt = blockIdx.x; rt < nTiles; rt += gridDim.x) {
        int arow = rt * 16 + m16;
        short8 a[8];
#pragma unroll
        for (int s = 0; s < 8; s++)
            a[s] = *(const short8*)(S + (size_t)arow * 256 + s * 32 + q * 8);

        f32x4 acc[4];
#pragma unroll
        for (int cc = 0; cc < 4; cc++) acc[cc] = (f32x4){0.f, 0.f, 0.f, 0.f};

#pragma unroll
        for (int s = 0; s < 8; s++)
#pragma unroll
            for (int cc = 0; cc < 4; cc++)
                acc[cc] = __builtin_amdgcn_mfma_f32_16x16x32_bf16(a[s], b[s][cc], acc[cc], 0, 0, 0);

        // C/D layout: col = lane&15, row = (lane>>4)*4 + reg
        int orow0 = rt * 16 + q * 4;
#pragma unroll
        for (int cc = 0; cc < 4; cc++) {
            int colv = (wave * 4 + cc) * 16 + m16;
#pragma unroll
            for (int r = 0; r < 4; r++) {
                float ov = acc[cc][r] + bv[cc];
                if (NT) __builtin_nontemporal_store(ov, &C[(size_t)(orow0 + r) * 256 + colv]);
                else    C[(size_t)(orow0 + r) * 256 + colv] = ov;
            }
        }
        if (Hb != nullptr) {
#pragma unroll
            for (int cc = 0; cc < 4; cc++) {
                int colv = (wave * 4 + cc) * 16 + m16;
#pragma unroll
                for (int r = 0; r < 4; r++)
                    Hb[(size_t)(orow0 + r) * 256 + colv] = f2bf(fmaxf(acc[cc][r] + bv[cc], 0.f));
            }
        }
    }
}

// ---------------- fused mean-pool + MLP head per graph (batch sorted) ----------------
__global__ __launch_bounds__(1024) void k_poolmlp(const float* __restrict__ C3,
                                                  const int* __restrict__ batch, int N,
                                                  float* __restrict__ pooled,
                                                  const float* __restrict__ L1w,
                                                  const float* __restrict__ L1b,
                                                  const float* __restrict__ L2w,
                                                  const float* __restrict__ L2b,
                                                  const float* __restrict__ L3w,
                                                  const float* __restrict__ L3b,
                                                  float* __restrict__ out) {
    int g = blockIdx.x;
    __shared__ int range[2];
    __shared__ float part[4][256];
    __shared__ float pl[256];
    __shared__ float o1[64];
    __shared__ float o2[32];
    if (threadIdx.x == 0 && threadIdx.y == 0) {
        int lo = 0, hi = N;
        while (lo < hi) { int mid = (lo + hi) >> 1; if (batch[mid] < g) lo = mid + 1; else hi = mid; }
        range[0] = lo;
        int lo2 = lo, hi2 = N;
        while (lo2 < hi2) { int mid = (lo2 + hi2) >> 1; if (batch[mid] < g + 1) lo2 = mid + 1; else hi2 = mid; }
        range[1] = lo2;
    }
    __syncthreads();
    int start = range[0], end = range[1];
    int f = threadIdx.x;
    float s = 0.f;
    for (int i = start + threadIdx.y; i < end; i += 4)
        s += fmaxf(C3[(size_t)i * 256 + f], 0.f);
    part[threadIdx.y][f] = s;
    __syncthreads();
    if (threadIdx.y == 0) {
        float tot = part[0][f] + part[1][f] + part[2][f] + part[3][f];
        int cnt = end - start;
        float pv = tot / (float)(cnt > 0 ? cnt : 1);
        pooled[g * 256 + f] = pv;
        pl[f] = pv;
    }
    __syncthreads();
    if (threadIdx.y == 0 && f < 64) {
        float s1 = L1b[f];
        for (int k = 0; k < 256; k++) s1 = fmaf(pl[k], L1w[k * 64 + f], s1);
        o1[f] = fmaxf(s1, 0.f);
    }
    __syncthreads();
    if (threadIdx.y == 0 && f < 32) {
        float s2 = L2b[f];
        for (int k = 0; k < 64; k++) s2 = fmaf(o1[k], L2w[k * 32 + f], s2);
        o2[f] = fmaxf(s2, 0.f);
    }
    __syncthreads();
    if (threadIdx.y == 0 && f < 2) {
        float s3 = L3b[f];
        for (int k = 0; k < 32; k++) s3 = fmaf(o2[k], L3w[k * 2 + f], s3);
        out[g * 2 + f] = fmaxf(s3, 0.f);
    }
}

extern "C" void kernel_launch(void* const* d_in, const int* in_sizes, int n_in,
                              void* d_out, int out_size, void* d_ws, size_t ws_size,
                              hipStream_t stream) {
    const float* x   = (const float*)d_in[0];
    const int*   ei  = (const int*)d_in[1];
    const float* ea  = (const float*)d_in[2];
    const int*   bat = (const int*)d_in[3];
    const float* W1  = (const float*)d_in[4];
    const float* b1  = (const float*)d_in[5];
    const float* W2  = (const float*)d_in[6];
    const float* b2  = (const float*)d_in[7];
    const float* W3  = (const float*)d_in[8];
    const float* b3  = (const float*)d_in[9];
    const float* L1w = (const float*)d_in[10];
    const float* L1b = (const float*)d_in[11];
    const float* L2w = (const float*)d_in[12];
    const float* L2b = (const float*)d_in[13];
    const float* L3w = (const float*)d_in[14];
    const float* L3b = (const float*)d_in[15];

    const int N = N_NODES, E = N_EDGES;
    const int* srcp = ei;
    const int* dstp = ei + E;

    // d_out layout (fp32 elements): out[256] | pooled[32768] | c1 | c2 | c3
    float* out_p    = (float*)d_out;
    float* pooled_p = out_p + 256;
    float* c1_p     = out_p + 33024;
    float* c2_p     = c1_p + (size_t)N * FDIM;
    float* c3_p     = c2_p + (size_t)N * FDIM;

    // workspace carve (bytes)
    char* ws = (char*)d_ws;
    size_t off = 0;
    unsigned short* Sb  = (unsigned short*)(ws + off); off += (size_t)(N + 64) * FDIM * 2;  // 25.6 MB
    unsigned short* Wp1 = (unsigned short*)(ws + off); off += 65536 * 2;
    unsigned short* Wp2 = (unsigned short*)(ws + off); off += 65536 * 2;
    unsigned short* Wp3 = (unsigned short*)(ws + off); off += 65536 * 2;
    float* dinv    = (float*)(ws + off); off += (size_t)N * 4;
    float* deg     = (float*)(ws + off); off += (size_t)N * 4;
    int*   cnt     = (int*)(ws + off);   off += (size_t)N * 4;
    int*   row_ptr = (int*)(ws + off);   off += ((size_t)N + 16) * 4;
    int*   cursor  = (int*)(ws + off);   off += (size_t)N * 4;
    int2*  cv      = (int2*)(ws + off);  off += (size_t)E * 8;
    int*   partial = (int*)(ws + off);   off += 64 * 4;
    // bf16 gather buffer (x-cast, then relu(c1)/relu(c2) from GEMM epilogue)
    unsigned short* Hb = (unsigned short*)(ws + off); off += (size_t)(N + 64) * FDIM * 2;
    bool use_bf = (ws_size >= off);
    (void)n_in; (void)in_sizes; (void)out_size;

    int nb256 = (N + 255) / 256;
    int eb256 = (E + 255) / 256;
    int nb1024 = (N + 1023) / 1024;          // 49 scan blocks

    if (use_bf) {
        k_prep<<<ZBLK + XBLK + RBLK, 256, 0, stream>>>(deg, cnt, x, Hb, W1, W2, W3, Wp1);
    } else {
        k_prep<<<ZBLK + RBLK, 256, 0, stream>>>(deg, cnt, x, /*Xb unused in zero/repack ranges*/ (unsigned short*)Sb, W1, W2, W3, Wp1);
        // note: without Hb the xcast range is skipped (grid excludes it); repack range
        // indices shift, so redo repack addressing: simplest is full grid with Sb as dummy
        // — but Sb is needed later. Launch full prep writing xcast into Sb (overwritten later).
        k_prep<<<ZBLK + XBLK + RBLK, 256, 0, stream>>>(deg, cnt, x, (unsigned short*)Sb, W1, W2, W3, Wp1);
    }
    k_deg<<<eb256, 256, 0, stream>>>(dstp, ea, deg, cnt, E);
    k_scan1<<<nb1024, 1024, 0, stream>>>(cnt, deg, dinv, row_ptr, partial, N);
    k_scan2<<<nb256, 256, 0, stream>>>(row_ptr, cursor, partial, nb1024, N);
    k_scatter<<<eb256, 256, 0, stream>>>(srcp, dstp, ea, dinv, cursor, cv, E);

    int agg_blocks  = (N + 3) / 4;           // 12500
    int nTiles      = N / 16;                // 3125
    int gemm_blocks = 512;                   // 2 blocks/CU resident, grid-stride

    if (use_bf) {
        // layer 1
        k_agg_bf<<<agg_blocks, 256, 0, stream>>>(Hb, row_ptr, cv, dinv, Sb, N);
        k_gemm2<true><<<gemm_blocks, 256, 0, stream>>>(Sb, Wp1, b1, c1_p, Hb, nTiles);
        // layer 2
        k_agg_bf<<<agg_blocks, 256, 0, stream>>>(Hb, row_ptr, cv, dinv, Sb, N);
        k_gemm2<true><<<gemm_blocks, 256, 0, stream>>>(Sb, Wp2, b2, c2_p, Hb, nTiles);
        // layer 3
        k_agg_bf<<<agg_blocks, 256, 0, stream>>>(Hb, row_ptr, cv, dinv, Sb, N);
        k_gemm2<false><<<gemm_blocks, 256, 0, stream>>>(Sb, Wp3, b3, c3_p, nullptr, nTiles);
    } else {
        // fp32-gather fallback
        k_agg<false><<<agg_blocks, 256, 0, stream>>>(x, row_ptr, cv, dinv, Sb, N);
        k_gemm2<false><<<gemm_blocks, 256, 0, stream>>>(Sb, Wp1, b1, c1_p, nullptr, nTiles);
        k_agg<true><<<agg_blocks, 256, 0, stream>>>(c1_p, row_ptr, cv, dinv, Sb, N);
        k_gemm2<false><<<gemm_blocks, 256, 0, stream>>>(Sb, Wp2, b2, c2_p, nullptr, nTiles);
        k_agg<true><<<agg_blocks, 256, 0, stream>>>(c2_p, row_ptr, cv, dinv, Sb, N);
        k_gemm2<false><<<gemm_blocks, 256, 0, stream>>>(Sb, Wp3, b3, c3_p, nullptr, nTiles);
    }

    // fused pool + head
    dim3 pb(256, 4);
    k_poolmlp<<<N_GRAPHS, pb, 0, stream>>>(c3_p, bat, N, pooled_p,
                                           L1w, L1b, L2w, L2b, L3w, L3b, out_p);
}